// Round 25
// baseline (207.044 us; speedup 1.0000x reference)
//
#include <hip/hip_runtime.h>
#include <hip/hip_bf16.h>
#include <stdint.h>

#define NN 4096
#define BATCH 1024
#define SEG 64          // carry granularity (steps)
#define NSEG 64
#define DPAD 8192
#define DGRP 128        // diagonals per pass3 block (sign-pure: NN-1 ≡ 127 mod 128)
#define TSEG 64         // steps per pass3 block (== SEG)

typedef __bf16 bf16x8 __attribute__((ext_vector_type(8)));
typedef float f32x4 __attribute__((ext_vector_type(4)));

__device__ __forceinline__ unsigned short f2bf(float f) {
    uint32_t u = __builtin_bit_cast(uint32_t, f);
    uint32_t r = (u + 0x7FFFu + ((u >> 16) & 1u)) >> 16;
    return (unsigned short)r;
}
__device__ __forceinline__ float bf2f(unsigned short u) {
    return __builtin_bit_cast(float, (uint32_t)u << 16);
}
__device__ __forceinline__ int iclamp(int v, int lo, int hi) {
    return v < lo ? lo : (v > hi ? hi : v);
}
__device__ __forceinline__ float4 ld4(const float* __restrict__ P, int p) {
    return make_float4(P[p], P[NN + p], P[2 * NN + p], P[3 * NN + p]);
}

// ---- pass 1 (+ fused x fp32->bf16 convert on blocks >= 2048) ----
__global__ __launch_bounds__(256) void k_pass1_convert(
        const float* __restrict__ G, const float* __restrict__ H,
        const float* __restrict__ sA, const float* __restrict__ sB,
        float2* __restrict__ seg,
        const float4* __restrict__ x4, ushort4* __restrict__ xb4) {
    int bx = blockIdx.x;
    if (bx >= 2048) {
        int t = (bx - 2048) * 256 + threadIdx.x;   // BATCH*NN/4 threads exactly
        float4 a = x4[t];
        ushort4 o;
        o.x = f2bf(a.x); o.y = f2bf(a.y); o.z = f2bf(a.z); o.w = f2bf(a.w);
        xb4[t] = o;
        return;
    }

    __shared__ float4 lBig[320];
    __shared__ float  lsBig[320];
    __shared__ float4 lSmall[64];
    __shared__ float  lsSmall[64];

    int s = bx >> 5;                 // segment 0..63
    int dd0 = (bx & 31) * 256;
    int t0 = s * SEG;
    int tid = threadIdx.x;
    bool neg = dd0 < 4096;

    int Lmax = neg ? (256 + dd0) : (8191 - dd0);
    if (t0 >= Lmax) return;

    int dd = dd0 + tid;
    int o = dd - (NN - 1);
    int ao = o < 0 ? -o : o;
    int L = NN - ao;
    bool active = t0 < L;
    int tend = t0 + SEG; if (tend > L) tend = L;

    if (neg) {
        int kb = t0 + 3840 - dd0;
        for (int j = tid; j < 320; j += 256) {
            lBig[j] = ld4(H, iclamp(kb + j, 0, NN - 1));
            lsBig[j] = sB[iclamp(kb - 1 + j, 0, NN - 2)];
        }
        if (tid < 64) {
            lSmall[tid] = ld4(G, iclamp(t0 + tid, 0, NN - 1));
            lsSmall[tid] = sA[iclamp(t0 + tid - 1, 0, NN - 2)];
        }
        __syncthreads();
        if (!active) return;
        int off = 255 - tid;
        float M = 0.f, Aacc = 1.f;
        for (int t = t0; t < tend; ++t) {
            int tl = t - t0;
            float4 g = lSmall[tl];
            float4 h = lBig[tl + off];
            float f = g.x * h.x + g.y * h.y + g.z * h.z + g.w * h.w;
            float c = (t == 0) ? 0.f : lsSmall[tl] * lsBig[tl + off];
            M = fmaf(c, M, f);
            Aacc *= c;
        }
        seg[(size_t)s * DPAD + dd] = make_float2(Aacc, M);
    } else {
        int ib = t0 + (dd0 - 4095);
        for (int j = tid; j < 320; j += 256) {
            lBig[j] = ld4(G, iclamp(ib + j, 0, NN - 1));
            lsBig[j] = sA[iclamp(ib - 1 + j, 0, NN - 2)];
        }
        if (tid < 64) {
            lSmall[tid] = ld4(H, iclamp(t0 + tid, 0, NN - 1));
            lsSmall[tid] = sB[iclamp(t0 + tid - 1, 0, NN - 2)];
        }
        __syncthreads();
        if (!active) return;
        float M = 0.f, Aacc = 1.f;
        for (int t = t0; t < tend; ++t) {
            int tl = t - t0;
            float4 g = lBig[tl + tid];
            float4 h = lSmall[tl];
            float f = g.x * h.x + g.y * h.y + g.z * h.z + g.w * h.w;
            float c = (t == 0) ? 0.f : lsBig[tl + tid] * lsSmall[tl];
            M = fmaf(c, M, f);
            Aacc *= c;
        }
        seg[(size_t)s * DPAD + dd] = make_float2(Aacc, M);
    }
}

// ---- pass 2: scan along each diagonal -> carry-in per segment ----
__global__ void k_pass2(const float2* __restrict__ seg, float* __restrict__ carr) {
    int dd = blockIdx.x * 256 + threadIdx.x;
    if (dd >= DPAD) return;
    int o = dd - (NN - 1);
    if (o > NN - 1) return;
    int ao = o < 0 ? -o : o;
    int L = NN - ao;
    int nseg = (L + SEG - 1) >> 6;
    float Min = 0.f;
    for (int s = 0; s < nseg; ++s) {
        carr[(size_t)s * DPAD + dd] = Min;
        float2 ab = seg[(size_t)s * DPAD + dd];
        Min = fmaf(ab.x, Min, ab.y);
    }
}

// ---- pass 3 (LDS-cached operands from G/H directly, 512 threads) ----
__global__ __launch_bounds__(512) void k_pass3t(
        const float* __restrict__ G, const float* __restrict__ H,
        const float* __restrict__ sA, const float* __restrict__ sB,
        const float* __restrict__ carr, unsigned short* __restrict__ V) {
    __shared__ unsigned short vals[191 * 64];
    __shared__ float4 cBig[192];
    __shared__ float  csBig[192];
    __shared__ float4 cSmall[64];
    __shared__ float  csSmall[64];

    int dg = blockIdx.x;   // 0..63
    int sg = blockIdx.y;   // 0..63
    int dd0 = dg * DGRP;
    int t0 = sg * TSEG;
    int o0 = dd0 - (NN - 1);
    int o_hi = o0 + DGRP - 1;

    int minabs = (o0 >= 0) ? o0 : ((o_hi < 0) ? -o_hi : 0);
    if (t0 >= NN - minabs) return;

    int tid = threadIdx.x;   // 0..511; compute lanes are tid<128

    if (o_hi <= 0) {
        int kb = t0 + 3968 - dd0;
        for (int j = tid; j < 192; j += 512) {
            cBig[j] = ld4(H, iclamp(kb + j, 0, NN - 1));
            csBig[j] = sB[iclamp(kb - 1 + j, 0, NN - 2)];
        }
        if (tid >= 256 && tid < 320) {
            int t = tid - 256;
            cSmall[t] = ld4(G, iclamp(t0 + t, 0, NN - 1));
            csSmall[t] = sA[iclamp(t0 + t - 1, 0, NN - 2)];
        }
        __syncthreads();

        if (tid < 128) {
            int dd = dd0 + tid;
            int o = dd - (NN - 1);
            float M = carr[(size_t)sg * DPAD + dd];
            int k0 = t0 - o;
            int off = 127 - tid;
#pragma unroll 4
            for (int tl = 0; tl < TSEG; ++tl) {
                int k = k0 + tl;
                float4 g = cSmall[tl];
                float4 h = cBig[tl + off];
                float f = g.x * h.x + g.y * h.y + g.z * h.z + g.w * h.w;
                float c = 0.f;
                if (t0 + tl != 0) c = csSmall[tl] * csBig[tl + off];
                M = fmaf(c, M, f);
                vals[tl * 128 + ((k & 127) ^ ((tl & 15) << 2))] = f2bf(M);
            }
        }
        __syncthreads();

        int row_sub = tid >> 5, csub = tid & 31;
        for (int rb = 0; rb < TSEG; rb += 16) {
            int tl = rb + row_sub;
            int i = t0 + tl;
            int swz = (tl & 15) << 2;
            int k_lo = i - o_hi;
            int k_hi = i - o0; if (k_hi > NN - 1) k_hi = NN - 1;
            size_t rowbase = (size_t)i * NN;
            int cb_first = k_lo >> 2, cb_last = k_hi >> 2;
            for (int cc = cb_first + csub; cc <= cb_last; cc += 32) {
                int kb2 = cc << 2;
                if (kb2 >= k_lo && kb2 + 3 <= k_hi) {
                    int c0 = (kb2 & 127) ^ swz;
                    *(ushort4*)&V[rowbase + kb2] = *(const ushort4*)&vals[tl * 128 + c0];
                } else {
#pragma unroll
                    for (int j = 0; j < 4; ++j) {
                        int k = kb2 + j;
                        if (k < k_lo || k > k_hi) continue;
                        V[rowbase + k] = vals[tl * 128 + ((k & 127) ^ swz)];
                    }
                }
            }
        }
    } else {
        int ib = t0 + o0;
        for (int j = tid; j < 192; j += 512) {
            cBig[j] = ld4(G, iclamp(ib + j, 0, NN - 1));
            csBig[j] = sA[iclamp(ib - 1 + j, 0, NN - 2)];
        }
        if (tid >= 256 && tid < 320) {
            int t = tid - 256;
            cSmall[t] = ld4(H, iclamp(t0 + t, 0, NN - 1));
            csSmall[t] = sB[iclamp(t0 + t - 1, 0, NN - 2)];
        }
        __syncthreads();

        if (tid < 128) {
            int dd = dd0 + tid;
            float M = carr[(size_t)sg * DPAD + dd];
#pragma unroll 4
            for (int tl = 0; tl < TSEG; ++tl) {
                int k = t0 + tl;
                float4 g = cBig[tl + tid];
                float4 h = cSmall[tl];
                float f = g.x * h.x + g.y * h.y + g.z * h.z + g.w * h.w;
                float c = 0.f;
                if (t0 + tl != 0) c = csBig[tl + tid] * csSmall[tl];
                M = fmaf(c, M, f);
                int rr = tl + tid;
                vals[rr * 64 + ((k & 63) ^ ((rr & 15) << 2))] = f2bf(M);
            }
        }
        __syncthreads();

        int i_lo = t0 + o0;
        int i_hi = t0 + TSEG - 1 + o_hi; if (i_hi > NN - 1) i_hi = NN - 1;
        int nrows = i_hi - i_lo + 1;
        int row_sub = tid >> 4, csub = tid & 15;
        for (int rb = 0; rb < nrows; rb += 32) {
            int rr = rb + row_sub;
            int i = i_lo + rr;
            if (i > i_hi) continue;
            int swz = (rr & 15) << 2;
            int k_lo = i - o_hi; if (k_lo < t0) k_lo = t0;
            int k_hi = i - o0;  if (k_hi > t0 + TSEG - 1) k_hi = t0 + TSEG - 1;
            size_t rowbase = (size_t)i * NN;
            int cb_first = k_lo >> 2, cb_last = k_hi >> 2;
            for (int cc = cb_first + csub; cc <= cb_last; cc += 16) {
                int kb2 = cc << 2;
                if (kb2 >= k_lo && kb2 + 3 <= k_hi) {
                    int c0 = (kb2 & 63) ^ swz;
                    *(ushort4*)&V[rowbase + kb2] = *(const ushort4*)&vals[rr * 64 + c0];
                } else {
#pragma unroll
                    for (int j = 0; j < 4; ++j) {
                        int k = kb2 + j;
                        if (k < k_lo || k > k_hi) continue;
                        V[rowbase + k] = vals[rr * 64 + ((k & 63) ^ swz)];
                    }
                }
            }
        }
    }
}

// ---- split-K=4 GEMM with fused split-K fixup: 256x256 tile, 8 waves, BK=64,
// 2-phase double-buffer, T2 swizzle, bf16 partials. The 4th block to finish a
// (bm,bn) tile reduces all 4 partials (fixed z order -> deterministic) + bias.
__global__ __launch_bounds__(512, 2) void k_gemm_sk4(const unsigned short* __restrict__ A,
                                                     const unsigned short* __restrict__ Bv,
                                                     unsigned short* __restrict__ part,
                                                     unsigned* __restrict__ cnt,
                                                     float* __restrict__ C,
                                                     const float* __restrict__ bias) {
    __shared__ unsigned short lA[2][256 * 64];   // 2 x 32 KB
    __shared__ unsigned short lB[2][256 * 64];   // 2 x 32 KB
    __shared__ unsigned sIsLast;

    int flat = blockIdx.x;
    int xcd = flat & 7;
    int local = flat >> 3;            // 0..31
    int bz = xcd >> 1;
    int bn = (xcd & 1) * 8 + (local >> 2);
    int bm = local & 3;

    int tid = threadIdx.x;
    int lane = tid & 63;
    int wid = tid >> 6;               // 0..7
    int wm = wid >> 2;                // 0..1  (M half)
    int wn = wid & 3;                 // 0..3  (N quarter)

    int kbase = bz * (NN / 4);

    size_t srcOff[4];
    int ldsOff[4];
#pragma unroll
    for (int c = 0; c < 4; ++c) {
        int idx = c * 512 + tid;
        int row = idx >> 3;
        int cbyte = (idx & 7) << 4;
        srcOff[c] = (size_t)row * NN + (size_t)((cbyte ^ ((row & 7) << 4)) >> 1);
        ldsOff[c] = idx * 8;
    }
    const unsigned short* Abase = A + (size_t)(bm * 256) * NN + kbase;
    const unsigned short* Bbase = Bv + (size_t)(bn * 256) * NN + kbase;

    int la15 = lane & 15, hi = lane >> 4;
    int swb = (lane & 7) << 4;
    int ce0 = ((hi * 16) ^ swb) >> 1;
    int ce1 = ((64 + hi * 16) ^ swb) >> 1;

    f32x4 acc[8][4];
#pragma unroll
    for (int i = 0; i < 8; ++i)
#pragma unroll
        for (int j = 0; j < 4; ++j) acc[i][j] = (f32x4){0.f, 0.f, 0.f, 0.f};

#define STAGE_ALL(slot, kt)                                                          \
    do {                                                                             \
        _Pragma("unroll") for (int c = 0; c < 4; ++c) {                              \
            __builtin_amdgcn_global_load_lds(                                        \
                (const __attribute__((address_space(1))) uint32_t*)(Abase + (size_t)(kt) * 64 + srcOff[c]), \
                (__attribute__((address_space(3))) uint32_t*)(&lA[slot][0] + ldsOff[c]), 16, 0, 0); \
            __builtin_amdgcn_global_load_lds(                                        \
                (const __attribute__((address_space(1))) uint32_t*)(Bbase + (size_t)(kt) * 64 + srcOff[c]), \
                (__attribute__((address_space(3))) uint32_t*)(&lB[slot][0] + ldsOff[c]), 16, 0, 0); \
        }                                                                            \
    } while (0)

#define COMPUTE(slot)                                                                \
    do {                                                                             \
        _Pragma("unroll") for (int kk = 0; kk < 2; ++kk) {                           \
            int ce = kk ? ce1 : ce0;                                                 \
            bf16x8 af[8], bfr[4];                                                    \
            _Pragma("unroll") for (int mf = 0; mf < 8; ++mf)                         \
                af[mf] = *(const bf16x8*)&lA[slot][(wm * 128 + mf * 16 + la15) * 64 + ce]; \
            _Pragma("unroll") for (int nf = 0; nf < 4; ++nf)                         \
                bfr[nf] = *(const bf16x8*)&lB[slot][(wn * 64 + nf * 16 + la15) * 64 + ce]; \
            __builtin_amdgcn_s_setprio(1);                                           \
            _Pragma("unroll") for (int mf = 0; mf < 8; ++mf)                         \
            _Pragma("unroll") for (int nf = 0; nf < 4; ++nf)                         \
                acc[mf][nf] = __builtin_amdgcn_mfma_f32_16x16x32_bf16(af[mf], bfr[nf], acc[mf][nf], 0, 0, 0); \
            __builtin_amdgcn_s_setprio(0);                                           \
        }                                                                            \
    } while (0)

    STAGE_ALL(0, 0);
    for (int u = 0; u < 16; ++u) {
        int s = u & 1;
        __syncthreads();              // drains tile-u loads; orders vs slot-s rewrite
        if (u < 15) STAGE_ALL(s ^ 1, u + 1);   // in flight during COMPUTE
        COMPUTE(s);
    }
#undef STAGE_ALL
#undef COMPUTE

    unsigned short* dst = part + (size_t)bz * BATCH * NN;
#pragma unroll
    for (int mf = 0; mf < 8; ++mf)
#pragma unroll
        for (int nf = 0; nf < 4; ++nf) {
            f32x4 v = acc[mf][nf];
            int col = bn * 256 + wn * 64 + nf * 16 + la15;
            int r0 = bm * 256 + wm * 128 + mf * 16 + hi * 4;
#pragma unroll
            for (int r = 0; r < 4; ++r)
                dst[(size_t)(r0 + r) * NN + col] = f2bf(v[r]);
        }

    // ---- split-K fixup: 4th arriver reduces this (bm,bn) tile ----
    __threadfence();                  // release this block's partial stores
    __syncthreads();
    if (tid == 0) {
        unsigned old = atomicAdd(&cnt[bm * 16 + bn], 1u);
        sIsLast = (old == 3u) ? 1u : 0u;
    }
    __syncthreads();
    if (!sIsLast) return;
    __threadfence();                  // acquire other blocks' partial stores

    const ushort4* p4 = (const ushort4*)part;
    size_t zstride = (size_t)BATCH * NN / 4;      // in ushort4 units
    const float4* bias4 = (const float4*)bias;
    float4* C4 = (float4*)C;
    int rbase = bm * 256, cb = bn * 64;           // cb in float4/ushort4 units
    int rsub = tid >> 6, csub2 = tid & 63;        // 8 rows x 64 lanes
    for (int it = 0; it < 32; ++it) {
        int row = rbase + it * 8 + rsub;
        size_t idx = (size_t)row * (NN / 4) + cb + csub2;
        ushort4 a = p4[idx], b = p4[zstride + idx];
        ushort4 d = p4[2 * zstride + idx], f = p4[3 * zstride + idx];
        float4 e = bias4[cb + csub2];
        C4[idx] = make_float4(
            bf2f(a.x) + bf2f(b.x) + bf2f(d.x) + bf2f(f.x) + e.x,
            bf2f(a.y) + bf2f(b.y) + bf2f(d.y) + bf2f(f.y) + e.y,
            bf2f(a.z) + bf2f(b.z) + bf2f(d.z) + bf2f(f.z) + e.z,
            bf2f(a.w) + bf2f(b.w) + bf2f(d.w) + bf2f(f.w) + e.w);
    }
}

extern "C" void kernel_launch(void* const* d_in, const int* in_sizes, int n_in,
                              void* d_out, int out_size, void* d_ws, size_t ws_size,
                              hipStream_t stream) {
    (void)in_sizes; (void)n_in; (void)out_size; (void)ws_size;
    const float* x  = (const float*)d_in[0];
    const float* sA = (const float*)d_in[1];
    const float* sB = (const float*)d_in[2];
    const float* G  = (const float*)d_in[3];
    const float* H  = (const float*)d_in[4];
    const float* bias = (const float*)d_in[5];
    float* out = (float*)d_out;

    char* ws = (char*)d_ws;
    unsigned short* V  = (unsigned short*)ws;               // 33,554,432 B
    float2* seg = (float2*)ws;                              // 4 MB, aliased on V (dead before pass3)
    unsigned short* xb = (unsigned short*)(ws + 33554432);  // 8,388,608 B
    float* carr = (float*)(ws + 42074112);                  // 2,097,152 B (SEG=64)
    unsigned short* part = (unsigned short*)(ws + 44171264);// 4 x 8,388,608 B bf16
    unsigned* cnt = (unsigned*)(ws + 77725696);             // 256 B tile counters
    // total ws need: 77,725,952 B

    hipMemsetAsync((void*)cnt, 0, 64 * sizeof(unsigned), stream);
    hipLaunchKernelGGL(k_pass1_convert, dim3(2048 + (BATCH * NN / 4) / 256), dim3(256), 0, stream,
                       G, H, sA, sB, seg, (const float4*)x, (ushort4*)xb);
    hipLaunchKernelGGL(k_pass2, dim3(DPAD / 256), dim3(256), 0, stream, seg, carr);
    hipLaunchKernelGGL(k_pass3t, dim3(DPAD / DGRP, NN / TSEG), dim3(512), 0, stream,
                       G, H, sA, sB, carr, V);
    hipLaunchKernelGGL(k_gemm_sk4, dim3(256), dim3(512), 0, stream,
                       xb, V, part, cnt, out, bias);
}

// Round 26
// 114.072 us; speedup vs baseline: 1.8150x; 1.8150x over previous
//
#include <hip/hip_runtime.h>
#include <hip/hip_bf16.h>
#include <stdint.h>

#define NN 4096
#define BATCH 1024
#define SEG 64          // carry granularity (steps)
#define NSEG 64
#define DPAD 8192
#define DGRP 128        // diagonals per pass3 block (sign-pure: NN-1 ≡ 127 mod 128)
#define TSEG 64         // steps per pass3 block (== SEG)

typedef __bf16 bf16x8 __attribute__((ext_vector_type(8)));
typedef float f32x4 __attribute__((ext_vector_type(4)));

__device__ __forceinline__ unsigned short f2bf(float f) {
    uint32_t u = __builtin_bit_cast(uint32_t, f);
    uint32_t r = (u + 0x7FFFu + ((u >> 16) & 1u)) >> 16;
    return (unsigned short)r;
}
__device__ __forceinline__ float bf2f(unsigned short u) {
    return __builtin_bit_cast(float, (uint32_t)u << 16);
}
__device__ __forceinline__ int iclamp(int v, int lo, int hi) {
    return v < lo ? lo : (v > hi ? hi : v);
}
__device__ __forceinline__ float4 ld4(const float* __restrict__ P, int p) {
    return make_float4(P[p], P[NN + p], P[2 * NN + p], P[3 * NN + p]);
}

// ---- pass 1 (+ fused x fp32->bf16 convert on blocks >= 2048) ----
__global__ __launch_bounds__(256) void k_pass1_convert(
        const float* __restrict__ G, const float* __restrict__ H,
        const float* __restrict__ sA, const float* __restrict__ sB,
        float2* __restrict__ seg,
        const float4* __restrict__ x4, ushort4* __restrict__ xb4) {
    int bx = blockIdx.x;
    if (bx >= 2048) {
        int t = (bx - 2048) * 256 + threadIdx.x;   // BATCH*NN/4 threads exactly
        float4 a = x4[t];
        ushort4 o;
        o.x = f2bf(a.x); o.y = f2bf(a.y); o.z = f2bf(a.z); o.w = f2bf(a.w);
        xb4[t] = o;
        return;
    }

    __shared__ float4 lBig[320];
    __shared__ float  lsBig[320];
    __shared__ float4 lSmall[64];
    __shared__ float  lsSmall[64];

    int s = bx >> 5;                 // segment 0..63
    int dd0 = (bx & 31) * 256;
    int t0 = s * SEG;
    int tid = threadIdx.x;
    bool neg = dd0 < 4096;

    int Lmax = neg ? (256 + dd0) : (8191 - dd0);
    if (t0 >= Lmax) return;

    int dd = dd0 + tid;
    int o = dd - (NN - 1);
    int ao = o < 0 ? -o : o;
    int L = NN - ao;
    bool active = t0 < L;
    int tend = t0 + SEG; if (tend > L) tend = L;

    if (neg) {
        int kb = t0 + 3840 - dd0;
        for (int j = tid; j < 320; j += 256) {
            lBig[j] = ld4(H, iclamp(kb + j, 0, NN - 1));
            lsBig[j] = sB[iclamp(kb - 1 + j, 0, NN - 2)];
        }
        if (tid < 64) {
            lSmall[tid] = ld4(G, iclamp(t0 + tid, 0, NN - 1));
            lsSmall[tid] = sA[iclamp(t0 + tid - 1, 0, NN - 2)];
        }
        __syncthreads();
        if (!active) return;
        int off = 255 - tid;
        float M = 0.f, Aacc = 1.f;
        for (int t = t0; t < tend; ++t) {
            int tl = t - t0;
            float4 g = lSmall[tl];
            float4 h = lBig[tl + off];
            float f = g.x * h.x + g.y * h.y + g.z * h.z + g.w * h.w;
            float c = (t == 0) ? 0.f : lsSmall[tl] * lsBig[tl + off];
            M = fmaf(c, M, f);
            Aacc *= c;
        }
        seg[(size_t)s * DPAD + dd] = make_float2(Aacc, M);
    } else {
        int ib = t0 + (dd0 - 4095);
        for (int j = tid; j < 320; j += 256) {
            lBig[j] = ld4(G, iclamp(ib + j, 0, NN - 1));
            lsBig[j] = sA[iclamp(ib - 1 + j, 0, NN - 2)];
        }
        if (tid < 64) {
            lSmall[tid] = ld4(H, iclamp(t0 + tid, 0, NN - 1));
            lsSmall[tid] = sB[iclamp(t0 + tid - 1, 0, NN - 2)];
        }
        __syncthreads();
        if (!active) return;
        float M = 0.f, Aacc = 1.f;
        for (int t = t0; t < tend; ++t) {
            int tl = t - t0;
            float4 g = lBig[tl + tid];
            float4 h = lSmall[tl];
            float f = g.x * h.x + g.y * h.y + g.z * h.z + g.w * h.w;
            float c = (t == 0) ? 0.f : lsBig[tl + tid] * lsSmall[tl];
            M = fmaf(c, M, f);
            Aacc *= c;
        }
        seg[(size_t)s * DPAD + dd] = make_float2(Aacc, M);
    }
}

// ---- pass 2: scan along each diagonal -> carry-in per segment ----
__global__ void k_pass2(const float2* __restrict__ seg, float* __restrict__ carr) {
    int dd = blockIdx.x * 256 + threadIdx.x;
    if (dd >= DPAD) return;
    int o = dd - (NN - 1);
    if (o > NN - 1) return;
    int ao = o < 0 ? -o : o;
    int L = NN - ao;
    int nseg = (L + SEG - 1) >> 6;
    float Min = 0.f;
    for (int s = 0; s < nseg; ++s) {
        carr[(size_t)s * DPAD + dd] = Min;
        float2 ab = seg[(size_t)s * DPAD + dd];
        Min = fmaf(ab.x, Min, ab.y);
    }
}

// ---- pass 3 (LDS-cached operands from G/H directly, 512 threads) ----
__global__ __launch_bounds__(512) void k_pass3t(
        const float* __restrict__ G, const float* __restrict__ H,
        const float* __restrict__ sA, const float* __restrict__ sB,
        const float* __restrict__ carr, unsigned short* __restrict__ V) {
    __shared__ unsigned short vals[191 * 64];
    __shared__ float4 cBig[192];
    __shared__ float  csBig[192];
    __shared__ float4 cSmall[64];
    __shared__ float  csSmall[64];

    int dg = blockIdx.x;   // 0..63
    int sg = blockIdx.y;   // 0..63
    int dd0 = dg * DGRP;
    int t0 = sg * TSEG;
    int o0 = dd0 - (NN - 1);
    int o_hi = o0 + DGRP - 1;

    int minabs = (o0 >= 0) ? o0 : ((o_hi < 0) ? -o_hi : 0);
    if (t0 >= NN - minabs) return;

    int tid = threadIdx.x;   // 0..511; compute lanes are tid<128

    if (o_hi <= 0) {
        int kb = t0 + 3968 - dd0;
        for (int j = tid; j < 192; j += 512) {
            cBig[j] = ld4(H, iclamp(kb + j, 0, NN - 1));
            csBig[j] = sB[iclamp(kb - 1 + j, 0, NN - 2)];
        }
        if (tid >= 256 && tid < 320) {
            int t = tid - 256;
            cSmall[t] = ld4(G, iclamp(t0 + t, 0, NN - 1));
            csSmall[t] = sA[iclamp(t0 + t - 1, 0, NN - 2)];
        }
        __syncthreads();

        if (tid < 128) {
            int dd = dd0 + tid;
            int o = dd - (NN - 1);
            float M = carr[(size_t)sg * DPAD + dd];
            int k0 = t0 - o;
            int off = 127 - tid;
#pragma unroll 4
            for (int tl = 0; tl < TSEG; ++tl) {
                int k = k0 + tl;
                float4 g = cSmall[tl];
                float4 h = cBig[tl + off];
                float f = g.x * h.x + g.y * h.y + g.z * h.z + g.w * h.w;
                float c = 0.f;
                if (t0 + tl != 0) c = csSmall[tl] * csBig[tl + off];
                M = fmaf(c, M, f);
                vals[tl * 128 + ((k & 127) ^ ((tl & 15) << 2))] = f2bf(M);
            }
        }
        __syncthreads();

        int row_sub = tid >> 5, csub = tid & 31;
        for (int rb = 0; rb < TSEG; rb += 16) {
            int tl = rb + row_sub;
            int i = t0 + tl;
            int swz = (tl & 15) << 2;
            int k_lo = i - o_hi;
            int k_hi = i - o0; if (k_hi > NN - 1) k_hi = NN - 1;
            size_t rowbase = (size_t)i * NN;
            int cb_first = k_lo >> 2, cb_last = k_hi >> 2;
            for (int cc = cb_first + csub; cc <= cb_last; cc += 32) {
                int kb2 = cc << 2;
                if (kb2 >= k_lo && kb2 + 3 <= k_hi) {
                    int c0 = (kb2 & 127) ^ swz;
                    *(ushort4*)&V[rowbase + kb2] = *(const ushort4*)&vals[tl * 128 + c0];
                } else {
#pragma unroll
                    for (int j = 0; j < 4; ++j) {
                        int k = kb2 + j;
                        if (k < k_lo || k > k_hi) continue;
                        V[rowbase + k] = vals[tl * 128 + ((k & 127) ^ swz)];
                    }
                }
            }
        }
    } else {
        int ib = t0 + o0;
        for (int j = tid; j < 192; j += 512) {
            cBig[j] = ld4(G, iclamp(ib + j, 0, NN - 1));
            csBig[j] = sA[iclamp(ib - 1 + j, 0, NN - 2)];
        }
        if (tid >= 256 && tid < 320) {
            int t = tid - 256;
            cSmall[t] = ld4(H, iclamp(t0 + t, 0, NN - 1));
            csSmall[t] = sB[iclamp(t0 + t - 1, 0, NN - 2)];
        }
        __syncthreads();

        if (tid < 128) {
            int dd = dd0 + tid;
            float M = carr[(size_t)sg * DPAD + dd];
#pragma unroll 4
            for (int tl = 0; tl < TSEG; ++tl) {
                int k = t0 + tl;
                float4 g = cBig[tl + tid];
                float4 h = cSmall[tl];
                float f = g.x * h.x + g.y * h.y + g.z * h.z + g.w * h.w;
                float c = 0.f;
                if (t0 + tl != 0) c = csBig[tl + tid] * csSmall[tl];
                M = fmaf(c, M, f);
                int rr = tl + tid;
                vals[rr * 64 + ((k & 63) ^ ((rr & 15) << 2))] = f2bf(M);
            }
        }
        __syncthreads();

        int i_lo = t0 + o0;
        int i_hi = t0 + TSEG - 1 + o_hi; if (i_hi > NN - 1) i_hi = NN - 1;
        int nrows = i_hi - i_lo + 1;
        int row_sub = tid >> 4, csub = tid & 15;
        for (int rb = 0; rb < nrows; rb += 32) {
            int rr = rb + row_sub;
            int i = i_lo + rr;
            if (i > i_hi) continue;
            int swz = (rr & 15) << 2;
            int k_lo = i - o_hi; if (k_lo < t0) k_lo = t0;
            int k_hi = i - o0;  if (k_hi > t0 + TSEG - 1) k_hi = t0 + TSEG - 1;
            size_t rowbase = (size_t)i * NN;
            int cb_first = k_lo >> 2, cb_last = k_hi >> 2;
            for (int cc = cb_first + csub; cc <= cb_last; cc += 16) {
                int kb2 = cc << 2;
                if (kb2 >= k_lo && kb2 + 3 <= k_hi) {
                    int c0 = (kb2 & 63) ^ swz;
                    *(ushort4*)&V[rowbase + kb2] = *(const ushort4*)&vals[rr * 64 + c0];
                } else {
#pragma unroll
                    for (int j = 0; j < 4; ++j) {
                        int k = kb2 + j;
                        if (k < k_lo || k > k_hi) continue;
                        V[rowbase + k] = vals[rr * 64 + ((k & 63) ^ swz)];
                    }
                }
            }
        }
    }
}

// ---- split-K=4 GEMM (measured-best): 256x256 tile, 8 waves, BK=64, 2-phase
// double-buffer, T2 swizzle, ALL z -> bf16 partials. 256 blocks, 512 threads.
__global__ __launch_bounds__(512, 2) void k_gemm_sk4(const unsigned short* __restrict__ A,
                                                     const unsigned short* __restrict__ Bv,
                                                     unsigned short* __restrict__ part) {
    __shared__ unsigned short lA[2][256 * 64];   // 2 x 32 KB
    __shared__ unsigned short lB[2][256 * 64];   // 2 x 32 KB

    int flat = blockIdx.x;
    int xcd = flat & 7;
    int local = flat >> 3;            // 0..31
    int bz = xcd >> 1;
    int bn = (xcd & 1) * 8 + (local >> 2);
    int bm = local & 3;

    int tid = threadIdx.x;
    int lane = tid & 63;
    int wid = tid >> 6;               // 0..7
    int wm = wid >> 2;                // 0..1  (M half)
    int wn = wid & 3;                 // 0..3  (N quarter)

    int kbase = bz * (NN / 4);

    size_t srcOff[4];
    int ldsOff[4];
#pragma unroll
    for (int c = 0; c < 4; ++c) {
        int idx = c * 512 + tid;
        int row = idx >> 3;
        int cbyte = (idx & 7) << 4;
        srcOff[c] = (size_t)row * NN + (size_t)((cbyte ^ ((row & 7) << 4)) >> 1);
        ldsOff[c] = idx * 8;
    }
    const unsigned short* Abase = A + (size_t)(bm * 256) * NN + kbase;
    const unsigned short* Bbase = Bv + (size_t)(bn * 256) * NN + kbase;

    int la15 = lane & 15, hi = lane >> 4;
    int swb = (lane & 7) << 4;
    int ce0 = ((hi * 16) ^ swb) >> 1;
    int ce1 = ((64 + hi * 16) ^ swb) >> 1;

    f32x4 acc[8][4];
#pragma unroll
    for (int i = 0; i < 8; ++i)
#pragma unroll
        for (int j = 0; j < 4; ++j) acc[i][j] = (f32x4){0.f, 0.f, 0.f, 0.f};

#define STAGE_ALL(slot, kt)                                                          \
    do {                                                                             \
        _Pragma("unroll") for (int c = 0; c < 4; ++c) {                              \
            __builtin_amdgcn_global_load_lds(                                        \
                (const __attribute__((address_space(1))) uint32_t*)(Abase + (size_t)(kt) * 64 + srcOff[c]), \
                (__attribute__((address_space(3))) uint32_t*)(&lA[slot][0] + ldsOff[c]), 16, 0, 0); \
            __builtin_amdgcn_global_load_lds(                                        \
                (const __attribute__((address_space(1))) uint32_t*)(Bbase + (size_t)(kt) * 64 + srcOff[c]), \
                (__attribute__((address_space(3))) uint32_t*)(&lB[slot][0] + ldsOff[c]), 16, 0, 0); \
        }                                                                            \
    } while (0)

#define COMPUTE(slot)                                                                \
    do {                                                                             \
        _Pragma("unroll") for (int kk = 0; kk < 2; ++kk) {                           \
            int ce = kk ? ce1 : ce0;                                                 \
            bf16x8 af[8], bfr[4];                                                    \
            _Pragma("unroll") for (int mf = 0; mf < 8; ++mf)                         \
                af[mf] = *(const bf16x8*)&lA[slot][(wm * 128 + mf * 16 + la15) * 64 + ce]; \
            _Pragma("unroll") for (int nf = 0; nf < 4; ++nf)                         \
                bfr[nf] = *(const bf16x8*)&lB[slot][(wn * 64 + nf * 16 + la15) * 64 + ce]; \
            __builtin_amdgcn_s_setprio(1);                                           \
            _Pragma("unroll") for (int mf = 0; mf < 8; ++mf)                         \
            _Pragma("unroll") for (int nf = 0; nf < 4; ++nf)                         \
                acc[mf][nf] = __builtin_amdgcn_mfma_f32_16x16x32_bf16(af[mf], bfr[nf], acc[mf][nf], 0, 0, 0); \
            __builtin_amdgcn_s_setprio(0);                                           \
        }                                                                            \
    } while (0)

    STAGE_ALL(0, 0);
    for (int u = 0; u < 16; ++u) {
        int s = u & 1;
        __syncthreads();              // drains tile-u loads; orders vs slot-s rewrite
        if (u < 15) STAGE_ALL(s ^ 1, u + 1);   // in flight during COMPUTE
        COMPUTE(s);
    }
#undef STAGE_ALL
#undef COMPUTE

    unsigned short* dst = part + (size_t)bz * BATCH * NN;
#pragma unroll
    for (int mf = 0; mf < 8; ++mf)
#pragma unroll
        for (int nf = 0; nf < 4; ++nf) {
            f32x4 v = acc[mf][nf];
            int col = bn * 256 + wn * 64 + nf * 16 + la15;
            int r0 = bm * 256 + wm * 128 + mf * 16 + hi * 4;
#pragma unroll
            for (int r = 0; r < 4; ++r)
                dst[(size_t)(r0 + r) * NN + col] = f2bf(v[r]);
        }
}

// ---- reduce4: out = bf16(p0)+bf16(p1)+bf16(p2)+bf16(p3) + bias ----
__global__ void k_reduce4(float4* __restrict__ C, const ushort4* __restrict__ p0,
                          const ushort4* __restrict__ p1, const ushort4* __restrict__ p2,
                          const ushort4* __restrict__ p3, const float4* __restrict__ bias4) {
    int idx = blockIdx.x * 256 + threadIdx.x;   // BATCH*NN/4 exactly
    ushort4 a = p0[idx], b = p1[idx], d = p2[idx], f = p3[idx];
    float4 e = bias4[idx & (NN / 4 - 1)];
    C[idx] = make_float4(
        bf2f(a.x) + bf2f(b.x) + bf2f(d.x) + bf2f(f.x) + e.x,
        bf2f(a.y) + bf2f(b.y) + bf2f(d.y) + bf2f(f.y) + e.y,
        bf2f(a.z) + bf2f(b.z) + bf2f(d.z) + bf2f(f.z) + e.z,
        bf2f(a.w) + bf2f(b.w) + bf2f(d.w) + bf2f(f.w) + e.w);
}

extern "C" void kernel_launch(void* const* d_in, const int* in_sizes, int n_in,
                              void* d_out, int out_size, void* d_ws, size_t ws_size,
                              hipStream_t stream) {
    (void)in_sizes; (void)n_in; (void)out_size; (void)ws_size;
    const float* x  = (const float*)d_in[0];
    const float* sA = (const float*)d_in[1];
    const float* sB = (const float*)d_in[2];
    const float* G  = (const float*)d_in[3];
    const float* H  = (const float*)d_in[4];
    const float* bias = (const float*)d_in[5];
    float* out = (float*)d_out;

    char* ws = (char*)d_ws;
    unsigned short* V  = (unsigned short*)ws;               // 33,554,432 B
    float2* seg = (float2*)ws;                              // 4 MB, aliased on V (dead before pass3)
    unsigned short* xb = (unsigned short*)(ws + 33554432);  // 8,388,608 B
    float* carr = (float*)(ws + 42074112);                  // 2,097,152 B (SEG=64)
    unsigned short* part = (unsigned short*)(ws + 44171264);// 4 x 8,388,608 B bf16
    // total ws need: 77,725,696 B

    hipLaunchKernelGGL(k_pass1_convert, dim3(2048 + (BATCH * NN / 4) / 256), dim3(256), 0, stream,
                       G, H, sA, sB, seg, (const float4*)x, (ushort4*)xb);
    hipLaunchKernelGGL(k_pass2, dim3(DPAD / 256), dim3(256), 0, stream, seg, carr);
    hipLaunchKernelGGL(k_pass3t, dim3(DPAD / DGRP, NN / TSEG), dim3(512), 0, stream,
                       G, H, sA, sB, carr, V);
    hipLaunchKernelGGL(k_gemm_sk4, dim3(256), dim3(512), 0, stream,
                       xb, V, part);
    hipLaunchKernelGGL(k_reduce4, dim3((BATCH * NN / 4) / 256), dim3(256), 0, stream,
                       (float4*)out, (const ushort4*)part,
                       (const ushort4*)(part + (size_t)BATCH * NN),
                       (const ushort4*)(part + 2ull * BATCH * NN),
                       (const ushort4*)(part + 3ull * BATCH * NN),
                       (const float4*)bias);
}